// Round 8
// baseline (3281.017 us; speedup 1.0000x reference)
//
#include <hip/hip_runtime.h>

#define B_ 128
#define T_ 512
#define D_ 256
#define H_ 512
#define GG_ 32   // gate groups: 16 hidden units each
#define BG_ 8    // batch groups: 16 rows each
#define SENT 0xFFFFFFFFu   // bf16-NaN in both halves: unreachable for finite h

typedef __bf16 bf16x8 __attribute__((ext_vector_type(8)));
typedef float  f32x4  __attribute__((ext_vector_type(4)));
typedef unsigned int u32;
typedef unsigned long long u64;
typedef u32    u32x4  __attribute__((ext_vector_type(4)));

// h exchange, T-INDEXED, SENTINEL-POISONED each launch. The data IS the flag:
// consumers atomic-load h words and retry while any word == SENT. Producer
// publish = ONE agent-scope store (no drain, no flag, no vote). Element =
// (bf16 hi) | (bf16 lo << 16); both halves NaN-coded only by the poison.
__device__ __align__(16) u32 g_ht[(size_t)T_ * B_ * H_];

__global__ void poison_ht() {
    const size_t n = (size_t)T_ * B_ * H_ / 4;
    const u32x4 v = {SENT, SENT, SENT, SENT};
    for (size_t i = (size_t)blockIdx.x * 256 + threadIdx.x; i < n; i += (size_t)gridDim.x * 256)
        __builtin_nontemporal_store(v, (u32x4*)g_ht + i);
}

__device__ inline float sigmoidf_(float v) { return 1.f / (1.f + __expf(-v)); }
__device__ inline float tanhf_(float v)    { return 1.f - 2.f / (__expf(2.f * v) + 1.f); }

// Grid: 256 blocks = 8 bg x 32 gg (1 block/CU guaranteed co-resident).
// Block: 256 threads = 4 waves; wave w owns K-slice [w*64,+64) of D, [w*128,+128) of H.
// No dispatch-order or XCD-placement assumptions: all sync is "load until the
// word stops being the sentinel" via agent-scope atomics (L1-bypassing).
__global__ __launch_bounds__(256, 1)
void lstm_persistent(const float* __restrict__ x,
                     const float* __restrict__ Wih,
                     const float* __restrict__ Whh,
                     const float* __restrict__ bih,
                     const float* __restrict__ bhh,
                     float* __restrict__ out,
                     u32* __restrict__ ws)
{
    const int tid  = threadIdx.x;
    const int wv   = tid >> 6;
    const int lane = tid & 63;
    const int bg   = blockIdx.x & (BG_ - 1);
    const int gg   = blockIdx.x >> 3;

    const int lm = lane & 15;   // M/N index in 16x16 MFMA tile
    const int lq = lane >> 4;   // k-quad (k offset = lq*8)

    // ---- Weight B-fragments in registers (bf16 hi/lo), loaded once ----
    bf16x8 wih_hi[2][4], wih_lo[2][4];   // [kt][gt], k = wv*64 + kt*32 + lq*8
    bf16x8 whh_hi[4][4], whh_lo[4][4];   // [kt][gt], k = wv*128 + kt*32 + lq*8

    for (int gt = 0; gt < 4; ++gt) {
        const int grow = gt * 512 + gg * 16 + lm;
#pragma unroll
        for (int kt = 0; kt < 2; ++kt) {
            const float* p = Wih + (size_t)grow * D_ + wv * 64 + kt * 32 + lq * 8;
            bf16x8 hi, lo;
#pragma unroll
            for (int e = 0; e < 8; ++e) {
                float v = p[e];
                __bf16 h1 = (__bf16)v;
                hi[e] = h1; lo[e] = (__bf16)(v - (float)h1);
            }
            wih_hi[kt][gt] = hi; wih_lo[kt][gt] = lo;
        }
#pragma unroll
        for (int kt = 0; kt < 4; ++kt) {
            const float* p = Whh + (size_t)grow * H_ + wv * 128 + kt * 32 + lq * 8;
            bf16x8 hi, lo;
#pragma unroll
            for (int e = 0; e < 8; ++e) {
                float v = p[e];
                __bf16 h1 = (__bf16)v;
                hi[e] = h1; lo[e] = (__bf16)(v - (float)h1);
            }
            whh_hi[kt][gt] = hi; whh_lo[kt][gt] = lo;
        }
    }

    // ---- Pointwise mapping: unit pj = tid&15, batch row pb = tid>>4 ----
    const int pj = tid & 15;
    const int pb = tid >> 4;
    float bias[4];
#pragma unroll
    for (int tp = 0; tp < 4; ++tp) {
        const int r = tp * 512 + gg * 16 + pj;
        bias[tp] = bih[r] + bhh[r];
    }
    float c = 0.f;

    // gate scratch (double-buffered) + 16-step out staging (per-thread column:
    // each thread writes/reads only s_hout[k][tid] -> no barrier needed).
    __shared__ __align__(16) float gp[2][4][64][17];
    __shared__ float s_hout[16][256];

    const int   xrow   = bg * 16 + lm;
    const float* xbase = x + (size_t)xrow * T_ * D_ + wv * 64;
    const u32 hoff_r = (u32)(bg * 16 + lm) * H_ + wv * 128;
    const u32 hoff_w = (u32)(bg * 16 + pb) * H_ + gg * 16 + pj;
    const size_t ooff = (size_t)(bg * 16 + pb) * H_ + gg * 16 + pj;

    // ---- x prefetch registers (x(t) resident in regs at top of step t) ----
    f32x4 xr0[2], xr1[2], xn0[2], xn1[2];
#pragma unroll
    for (int kt = 0; kt < 2; ++kt) {
        const float* p = xbase + kt * 32 + lq * 8;
        xr0[kt] = *(const f32x4*)p;
        xr1[kt] = *(const f32x4*)(p + 4);
    }

#define LOAD_HD() do {                                                                   \
        _Pragma("unroll") for (int kt = 0; kt < 4; ++kt)                                 \
        _Pragma("unroll") for (int e = 0; e < 4; ++e) {                                  \
            u64 v = __hip_atomic_load(qb + kt * 16 + e, __ATOMIC_RELAXED,                \
                                      __HIP_MEMORY_SCOPE_AGENT);                         \
            wd[kt][2 * e] = (u32)v; wd[kt][2 * e + 1] = (u32)(v >> 32);                  \
        }                                                                                \
    } while (0)

    for (int t = 0; t < T_; ++t) {
        f32x4 acc[4];
#pragma unroll
        for (int gt = 0; gt < 4; ++gt) acc[gt] = (f32x4){0.f, 0.f, 0.f, 0.f};

        // ---- issue h(t-1) sentinel loads FIRST; x-MFMA overlaps their latency ----
        u32 wd[4][8];
        const u64* qb = (const u64*)(g_ht + (size_t)(t > 0 ? t - 1 : 0) * (B_ * H_) + hoff_r) + lq * 4;
        if (t > 0) LOAD_HD();

        // ---- x-part MFMA from xr (loaded last step; long retired) ----
#pragma unroll
        for (int kt = 0; kt < 2; ++kt) {
            bf16x8 ahi, alo;
#pragma unroll
            for (int e = 0; e < 4; ++e) {
                __bf16 h1 = (__bf16)xr0[kt][e];
                ahi[e] = h1; alo[e] = (__bf16)(xr0[kt][e] - (float)h1);
                __bf16 h2 = (__bf16)xr1[kt][e];
                ahi[e + 4] = h2; alo[e + 4] = (__bf16)(xr1[kt][e] - (float)h2);
            }
#pragma unroll
            for (int gt = 0; gt < 4; ++gt) {
                acc[gt] = __builtin_amdgcn_mfma_f32_16x16x32_bf16(ahi, wih_hi[kt][gt], acc[gt], 0, 0, 0);
                acc[gt] = __builtin_amdgcn_mfma_f32_16x16x32_bf16(ahi, wih_lo[kt][gt], acc[gt], 0, 0, 0);
                acc[gt] = __builtin_amdgcn_mfma_f32_16x16x32_bf16(alo, wih_hi[kt][gt], acc[gt], 0, 0, 0);
            }
        }

        if (t > 0) {
            // ---- sentinel check + retry: the load IS the poll ----
            while (true) {
                int ok = 1;
#pragma unroll
                for (int kt = 0; kt < 4; ++kt)
#pragma unroll
                    for (int e = 0; e < 8; ++e) ok &= (wd[kt][e] != SENT);
                if (__all(ok)) break;
                __builtin_amdgcn_s_sleep(1);
                LOAD_HD();
            }
            __builtin_amdgcn_sched_barrier(0);

            // ---- h-part MFMA: round-6 verbatim mask/shift unpack (bit-exact) ----
#pragma unroll
            for (int kt = 0; kt < 4; ++kt) {
                bf16x8 ahi, alo;
#pragma unroll
                for (int e = 0; e < 8; ++e) {
                    const u32 w = wd[kt][e];
                    ahi[e] = __builtin_bit_cast(__bf16, (unsigned short)(w & 0xffffu));
                    alo[e] = __builtin_bit_cast(__bf16, (unsigned short)(w >> 16));
                }
#pragma unroll
                for (int gt = 0; gt < 4; ++gt) {
                    acc[gt] = __builtin_amdgcn_mfma_f32_16x16x32_bf16(ahi, whh_hi[kt][gt], acc[gt], 0, 0, 0);
                    acc[gt] = __builtin_amdgcn_mfma_f32_16x16x32_bf16(ahi, whh_lo[kt][gt], acc[gt], 0, 0, 0);
                    acc[gt] = __builtin_amdgcn_mfma_f32_16x16x32_bf16(alo, whh_hi[kt][gt], acc[gt], 0, 0, 0);
                }
            }
        }

        // ---- x(t+1) prefetch: fenced so it can't hoist above the sentinel loop
        // (older-in-FIFO HBM loads would tax every retry round's wait). ----
        __builtin_amdgcn_sched_barrier(0);
        if (t < T_ - 1) {
            const float* pn = xbase + (size_t)(t + 1) * D_;
#pragma unroll
            for (int kt = 0; kt < 2; ++kt) {
                const float* p = pn + kt * 32 + lq * 8;
                xn0[kt] = *(const f32x4*)p;
                xn1[kt] = *(const f32x4*)(p + 4);
            }
        }
        __builtin_amdgcn_sched_barrier(0);

        // ---- cross-wave K reduction via LDS (double-buffered) ----
        const int pbuf = t & 1;
#pragma unroll
        for (int gt = 0; gt < 4; ++gt)
            *(f32x4*)&gp[pbuf][wv][gt * 16 + lm][lq * 4] = acc[gt];
        __syncthreads();

        float gate[4];
#pragma unroll
        for (int tp = 0; tp < 4; ++tp) {
            const int g = tp * 16 + pj;
            gate[tp] = gp[pbuf][0][g][pb] + gp[pbuf][1][g][pb] +
                       gp[pbuf][2][g][pb] + gp[pbuf][3][g][pb] + bias[tp];
        }
        const float ig = sigmoidf_(gate[0]);
        const float fg = sigmoidf_(gate[1]);
        const float gv = tanhf_(gate[2]);
        const float og = sigmoidf_(gate[3]);
        c = fg * c + ig * gv;
        const float h = og * tanhf_(c);

        // ---- publish: ONE agent-scope store. No drain, no flag. ----
        const __bf16 hh = (__bf16)h;
        const __bf16 hl = (__bf16)(h - (float)hh);
        const u32 packed = (u32)__builtin_bit_cast(unsigned short, hh) |
                           ((u32)__builtin_bit_cast(unsigned short, hl) << 16);
        __hip_atomic_store(&g_ht[(size_t)t * (B_ * H_) + hoff_w], packed,
                           __ATOMIC_RELAXED, __HIP_MEMORY_SCOPE_AGENT);

        // ---- out staging: LDS now, burst of 16 NT stores every 16 steps so
        // HBM store acks hit the vmcnt FIFO once per 16 steps, not every step ----
        s_hout[t & 15][tid] = h;
        if ((t & 15) == 15) {
            const int t0 = t - 15;
#pragma unroll
            for (int k = 0; k < 16; ++k)
                __builtin_nontemporal_store(s_hout[k][tid], &out[(size_t)(t0 + k) * (B_ * H_) + ooff]);
        }

        // rotate x prefetch registers
#pragma unroll
        for (int kt = 0; kt < 2; ++kt) { xr0[kt] = xn0[kt]; xr1[kt] = xn1[kt]; }
    }
#undef LOAD_HD
}

extern "C" void kernel_launch(void* const* d_in, const int* in_sizes, int n_in,
                              void* d_out, int out_size, void* d_ws, size_t ws_size,
                              hipStream_t stream) {
    const float* x   = (const float*)d_in[0];
    const float* Wih = (const float*)d_in[1];
    const float* Whh = (const float*)d_in[2];
    const float* bih = (const float*)d_in[3];
    const float* bhh = (const float*)d_in[4];
    float* out = (float*)d_out;
    u32* ws = (u32*)d_ws;

    hipLaunchKernelGGL(poison_ht, dim3(2048), dim3(256), 0, stream);
    hipLaunchKernelGGL(lstm_persistent, dim3(GG_ * BG_), dim3(256), 0, stream,
                       x, Wih, Whh, bih, bhh, out, ws);
}